// Round 6
// baseline (334.879 us; speedup 1.0000x reference)
//
#include <hip/hip_runtime.h>
#include <stdint.h>

#define BB 16
#define HH 512
#define WW 512
#define HW (HH*WW)
#define NB 256

// Fused mask kernel geometry
#define YC 36        // owned rows per block
#define SROWS 64     // staged rows = YC + 2*14
#define MROWS 40     // mse rows = YC + 4 (blur needs +-2)
#define MPAD 132     // sMse row stride in words: 16B-aligned (132*4=528) -> b128 blur reads
#define NYCH 15      // ceil(512/36)

typedef float f32x4 __attribute__((ext_vector_type(4)));

// C plane byte layout (one byte per pixel, [side*BB+b][HW]):
//   bits 0-1: e = mask[2]+mask[3]  (0,1,2)
//   bit  2  : mask[0] > 0   (lip)
//   bit  3  : mask[1] > 0   (skin)
//   bit  4  : mask[4] > 0
//   bits 5-6: m_se (0,1,2)

__device__ __forceinline__ float denorm255(float x) {
    return fminf(fmaxf((x + 1.0f) * 0.5f, 0.0f), 1.0f) * 255.0f;
}
__device__ __forceinline__ float renorm_lut(int t) {
    return ((float)t / 255.0f) * 2.0f - 1.0f;
}
// byte-granular funnel shift: result byte j = byte (j+r) of (hi:lo), r in 0..3
__device__ __forceinline__ uint32_t alignb(uint32_t hi, uint32_t lo, int r) {
    return (uint32_t)(((((uint64_t)hi) << 32) | lo) >> (8 * r));
}

// 12 weighted histograms; 4 px per call
__device__ __forceinline__ void hist4(int* h, uint32_t cw,
                                      f32x4 v0, f32x4 v1, f32x4 v2)
{
    #pragma unroll
    for (int j = 0; j < 4; j++) {
        uint32_t pb = (cw >> (8 * j)) & 0xFFu;
        float d0 = denorm255(v0[j]);
        float d1 = denorm255(v1[j]);
        float d2 = denorm255(v2[j]);
        if (pb & 8u) {
            atomicAdd(&h[0 * NB + min((int)d0, 255)], 1);
            atomicAdd(&h[1 * NB + min((int)d1, 255)], 1);
            atomicAdd(&h[2 * NB + min((int)d2, 255)], 1);
        }
        if (pb & 16u) {
            atomicAdd(&h[3 * NB + min((int)d0, 255)], 1);
            atomicAdd(&h[4 * NB + min((int)d1, 255)], 1);
            atomicAdd(&h[5 * NB + min((int)d2, 255)], 1);
        }
        if (pb & 4u) {
            atomicAdd(&h[6 * NB + min((int)d0, 255)], 1);
            atomicAdd(&h[7 * NB + min((int)d1, 255)], 1);
            atomicAdd(&h[8 * NB + min((int)d2, 255)], 1);
        }
        int mei = (int)((pb >> 5) & 3u);
        if (mei) {
            float fm = (float)mei;
            atomicAdd(&h[ 9 * NB + min((int)(d0 * fm), 255)], mei);
            atomicAdd(&h[10 * NB + min((int)(d1 * fm), 255)], mei);
            atomicAdd(&h[11 * NB + min((int)(d2 * fm), 255)], mei);
        }
    }
}

// ---- K1 (fused): prep + hOR + vOR + m_se + blur + region histograms ----
// R6 schedule: phase-3 image loads software-pipelined (2-deep asm ping-pong,
// counted vmcnt(6), never drain-0 until tail); first 2 iterations issued
// BEFORE the phase-2a barrier; raw s_barrier + lgkmcnt(0) instead of
// __syncthreads (which drains vmcnt(0) and would kill the prefetch);
// phase-2b global stores moved AFTER phase 3 so stores stay out of the
// vmcnt count. sMse stride 132 keeps rows 16B-aligned (b128 blur reads).
__global__ void __launch_bounds__(256) fused_mask_kernel(
    const float* __restrict__ ms, const float* __restrict__ mr,
    const float* __restrict__ src, const float* __restrict__ tgt,
    uint32_t* __restrict__ C, uint32_t* __restrict__ mbs,
    int* __restrict__ hist)
{
    __shared__ uint32_t sHor[SROWS][128];
    __shared__ uint32_t sMse[MROWS][MPAD];
    __shared__ int h[2][12 * NB];           // hist replicas (per 4-wave half)

    // XCD swizzle (480 = 8 * 60, bijective)
    int blk  = (blockIdx.x & 7) * 60 + (blockIdx.x >> 3);
    int ych  = blk % NYCH;
    int sb   = blk / NYCH;            // side*16 + b
    int side = sb >> 4;
    int b    = sb & 15;
    int y0   = ych * YC;

    const float* base = (side ? mr : ms) + (size_t)b * 5 * HW;
    int r0 = threadIdx.x >> 5;        // 0..7
    int c  = threadIdx.x & 31;        // 16-px chunk within row

    // image pointers for phase 3
    int* hw = h[threadIdx.x >> 7];
    const float* img = (side ? tgt : src) + (size_t)b * 3 * HW;
    const float4* i0 = (const float4*)(img);
    const float4* i1 = (const float4*)(img + HW);
    const float4* i2 = (const float4*)(img + 2 * (size_t)HW);
    auto cidx_of = [&](int it) -> int {
        int idx = threadIdx.x + it * 256;
        int o = idx >> 6, g = idx & 63;
        int gyc = min(y0 + o, HH - 1);     // clamp: tail block re-reads row 511
        return gyc * 64 + g;
    };

    // zero hist replicas (drained by barrier-1's lgkmcnt(0))
    for (int i = threadIdx.x; i < 2 * 12 * NB; i += 256) ((int*)h)[i] = 0;

    // ---- Phase 1: load masks, pack C bits, horizontal +-12 OR (shfl) ----
    for (int it = 0; it < 8; ++it) {
        int L  = r0 + 8 * it;         // staged row 0..63
        int gy = y0 - 14 + L;         // global row
        bool inimg = (gy >= 0 && gy < HH);
        bool m1row = inimg && (L >= 12 && L < 52);   // plane1 needed (+-2)
        bool owned = inimg && (L >= 14 && L < 50);   // full C bits needed

        float4 v[5][4];
        #pragma unroll
        for (int p = 0; p < 5; p++)
            #pragma unroll
            for (int j = 0; j < 4; j++) v[p][j] = make_float4(0.f, 0.f, 0.f, 0.f);

        if (inimg) {
            const float* rowp = base + (size_t)gy * WW + 16 * c;
            const float4* p2 = (const float4*)(rowp + 2 * (size_t)HW);
            const float4* p3 = (const float4*)(rowp + 3 * (size_t)HW);
            #pragma unroll
            for (int j = 0; j < 4; j++) { v[2][j] = p2[j]; v[3][j] = p3[j]; }
            if (m1row) {
                const float4* p1 = (const float4*)(rowp + (size_t)HW);
                #pragma unroll
                for (int j = 0; j < 4; j++) v[1][j] = p1[j];
            }
            if (owned) {
                const float4* p0 = (const float4*)(rowp);
                const float4* p4 = (const float4*)(rowp + 4 * (size_t)HW);
                #pragma unroll
                for (int j = 0; j < 4; j++) { v[0][j] = p0[j]; v[4][j] = p4[j]; }
            }
        }

        uint32_t Wd[4], E[4];
        #pragma unroll
        for (int j = 0; j < 4; j++) {
            uint32_t wc = 0;
            #pragma unroll
            for (int k = 0; k < 4; k++) {
                float a0 = (&v[0][j].x)[k];
                float a1 = (&v[1][j].x)[k];
                float a2 = (&v[2][j].x)[k];
                float a3 = (&v[3][j].x)[k];
                float a4 = (&v[4][j].x)[k];
                uint32_t e  = (uint32_t)(a2 + a3);              // exact 0/1/2
                uint32_t pb = (a0 > 0.f ? 4u : 0u) | (a1 > 0.f ? 8u : 0u)
                            | (a4 > 0.f ? 16u : 0u);
                wc |= (e | pb) << (8 * k);
            }
            Wd[j] = wc;
            E[j]  = wc & 0x03030303u;
        }

        // halo: left lane supplies words 4c-3..4c-1, right lane 4c+4..4c+6
        uint32_t Lw[3], Rw[3];
        #pragma unroll
        for (int i = 0; i < 3; i++) {
            uint32_t lv = __shfl_up(E[i + 1], 1, 32);
            Lw[i] = (c == 0) ? 0u : lv;
            uint32_t rv = __shfl_down(E[i], 1, 32);
            Rw[i] = (c == 31) ? 0u : rv;
        }
        uint32_t arr[10] = {Lw[0], Lw[1], Lw[2], E[0], E[1], E[2], E[3],
                            Rw[0], Rw[1], Rw[2]};
        #pragma unroll
        for (int k = 0; k < 4; k++) {
            const int b3 = 3 + k;
            uint32_t a = arr[b3];
            #pragma unroll
            for (int s = 1; s <= 12; s++) {
                int ai = s >> 2, rrs = s & 3;
                uint32_t vp, vm;
                if (rrs == 0) {
                    vp = arr[b3 + ai];
                    vm = arr[b3 - ai];
                } else {
                    vp = alignb(arr[b3 + ai + 1], arr[b3 + ai], rrs);
                    int am = (s + 3) >> 2;
                    vm = alignb(arr[b3 - am + 1], arr[b3 - am], 4 - rrs);
                }
                a |= vp | vm;
            }
            sHor[L][4 * c + k] = Wd[k] | (a << 5);   // hOR value <=3 -> bits 5-6
        }
    }

    // issue the loads for phase-3 iterations 0 and 1 (f32x4 ping-pong sets);
    // their HBM latency hides under phase 2a (vOR). These survive the raw
    // s_barrier (no vmcnt drain, unlike __syncthreads).
    f32x4 A0, A1, A2, A3, A4, A5, B0, B1, B2, B3, B4, B5;
#define ISSUE(CIDX, R0, R1, R2, R3, R4, R5) do {                              \
    int _ci = (CIDX);                                                         \
    const float* _p0 = (const float*)(i0 + 2 * _ci);                          \
    const float* _p1 = (const float*)(i1 + 2 * _ci);                          \
    const float* _p2 = (const float*)(i2 + 2 * _ci);                          \
    asm volatile("global_load_dwordx4 %0, %1, off"           : "=v"(R0) : "v"(_p0)); \
    asm volatile("global_load_dwordx4 %0, %1, off offset:16" : "=v"(R1) : "v"(_p0)); \
    asm volatile("global_load_dwordx4 %0, %1, off"           : "=v"(R2) : "v"(_p1)); \
    asm volatile("global_load_dwordx4 %0, %1, off offset:16" : "=v"(R3) : "v"(_p1)); \
    asm volatile("global_load_dwordx4 %0, %1, off"           : "=v"(R4) : "v"(_p2)); \
    asm volatile("global_load_dwordx4 %0, %1, off offset:16" : "=v"(R5) : "v"(_p2)); \
} while (0)
    ISSUE(cidx_of(0), A0, A1, A2, A3, A4, A5);
    ISSUE(cidx_of(1), B0, B1, B2, B3, B4, B5);

    // barrier 1: own LDS writes drained, loads stay in flight
    asm volatile("s_waitcnt lgkmcnt(0)" ::: "memory");
    __builtin_amdgcn_s_barrier();

    // ---- Phase 2a: vertical +-12 OR, map 3->2, AND m1 -> sMse ----
    {
        int w  = threadIdx.x & 127;
        int mg = threadIdx.x >> 7;    // 0 or 1
        for (int k = 0; k < 20; ++k) {
            int m = mg * 20 + k;      // mse row: global y0-2+m
            uint32_t o = 0;
            #pragma unroll
            for (int dy = 0; dy < 25; ++dy) o |= sHor[m + dy][w];
            uint32_t vv = (o >> 5) & 0x03030303u;
            uint32_t t3 = vv & (vv >> 1) & 0x01010101u;   // byte==3 detector
            vv -= t3;                                      // map 3 -> 2
            uint32_t m1 = (sHor[m + 12][w] >> 3) & 0x01010101u;
            vv &= m1 * 3u;                                 // AND skin mask
            sMse[m][w] = vv;
        }
    }
    asm volatile("s_waitcnt lgkmcnt(0)" ::: "memory");
    __builtin_amdgcn_s_barrier();

    // ---- Phase 3: region histograms, 2-deep pipelined (9 iterations) ----
    // wait pattern: vmcnt(6) (other set outstanding) for it 0..7, vmcnt(0) tail.
#define STEP(IT, WAITN, R0, R1, R2, R3, R4, R5) do {                          \
    asm volatile("s_waitcnt vmcnt(" WAITN ")" ::: "memory");                  \
    __builtin_amdgcn_sched_barrier(0);                                        \
    int _idx = threadIdx.x + (IT) * 256;                                      \
    int _o = _idx >> 6, _g = _idx & 63;                                       \
    if (y0 + _o < HH) {                                                       \
        uint2 hv = *(const uint2*)&sHor[14 + _o][2 * _g];                     \
        uint2 mv = *(const uint2*)&sMse[_o + 2][2 * _g];                      \
        hist4(hw, (hv.x & 0x1F1F1F1Fu) | (mv.x << 5), R0, R2, R4);            \
        hist4(hw, (hv.y & 0x1F1F1F1Fu) | (mv.y << 5), R1, R3, R5);            \
    }                                                                         \
    if ((IT) + 2 < 9) ISSUE(cidx_of((IT) + 2), R0, R1, R2, R3, R4, R5);       \
} while (0)
    STEP(0, "6", A0, A1, A2, A3, A4, A5);
    STEP(1, "6", B0, B1, B2, B3, B4, B5);
    STEP(2, "6", A0, A1, A2, A3, A4, A5);
    STEP(3, "6", B0, B1, B2, B3, B4, B5);
    STEP(4, "6", A0, A1, A2, A3, A4, A5);
    STEP(5, "6", B0, B1, B2, B3, B4, B5);
    STEP(6, "6", A0, A1, A2, A3, A4, A5);
    STEP(7, "6", B0, B1, B2, B3, B4, B5);
    STEP(8, "0", A0, A1, A2, A3, A4, A5);
#undef STEP
#undef ISSUE

    // ---- Phase 2b (moved after ph3): C store (no RMW) + 5x5 blur (side 0) ----
    {
        int ck = threadIdx.x & 31;
        int rr = threadIdx.x >> 5;
        size_t plane = (size_t)(side * BB + b);
        uint32_t* Cp = C + plane * (HW / 4);
        uint32_t* Mp = mbs + (size_t)b * (HW / 4);
        for (int o = rr; o < YC; o += 8) {
            int gy = y0 + o;
            if (gy >= HH) break;
            uint4 cw;
            #pragma unroll
            for (int q = 0; q < 4; q++) {
                uint32_t b5 = sHor[14 + o][4 * ck + q] & 0x1F1F1F1Fu;
                uint32_t mv = sMse[o + 2][4 * ck + q];
                (&cw.x)[q] = b5 | (mv << 5);
            }
            *((uint4*)(Cp + (size_t)gy * 128 + 4 * ck)) = cw;

            if (side == 0) {
                uint32_t s[6] = {0u, 0u, 0u, 0u, 0u, 0u};
                #pragma unroll
                for (int dy = 0; dy < 5; dy++) {
                    const uint32_t* rp = sMse[o + dy];   // global gy-2+dy
                    if (ck > 0)  s[0] += rp[4 * ck - 1];
                    s[1] += rp[4 * ck + 0];
                    s[2] += rp[4 * ck + 1];
                    s[3] += rp[4 * ck + 2];
                    s[4] += rp[4 * ck + 3];
                    if (ck < 31) s[5] += rp[4 * ck + 4];
                }
                uint4 ob;
                #pragma unroll
                for (int k = 0; k < 4; k++) {
                    uint32_t vv = s[k + 1];
                    vv += alignb(s[k + 1], s[k],     2);
                    vv += alignb(s[k + 1], s[k],     3);
                    vv += alignb(s[k + 2], s[k + 1], 1);
                    vv += alignb(s[k + 2], s[k + 1], 2);
                    (&ob.x)[k] = vv;
                }
                *((uint4*)(Mp + (size_t)gy * 128 + 4 * ck)) = ob;
            }
        }
    }

    // barrier 3: all hist LDS atomics visible
    asm volatile("s_waitcnt lgkmcnt(0)" ::: "memory");
    __builtin_amdgcn_s_barrier();
    {
        int* gh = hist + (size_t)(b * 2 + side) * 12 * NB;
        for (int i = threadIdx.x; i < 12 * NB; i += 256) {
            int s = h[0][i] + h[1][i];
            if (s) atomicAdd(&gh[i], s);
        }
    }
}

// ---- K5: cdf + searchsorted -> 256-entry LUT per (b, region, channel) ----
__global__ void __launch_bounds__(NB) table_kernel(
    const int* __restrict__ hist, uint8_t* __restrict__ table)
{
    int idx = blockIdx.x;               // (b*4+rg)*3+c, 192 blocks
    int c = idx % 3; int rest = idx / 3; int rg = rest & 3; int b = rest >> 2;
    const int* hs = hist + ((size_t)((b * 2 + 0) * 4 + rg) * 3 + c) * NB;
    const int* hr = hist + ((size_t)((b * 2 + 1) * 4 + rg) * 3 + c) * NB;
    __shared__ int a[NB];
    __shared__ float cr[NB];
    int t = threadIdx.x;

    a[t] = hs[t];
    __syncthreads();
    for (int off = 1; off < NB; off <<= 1) {
        int v = (t >= off) ? a[t - off] : 0;
        __syncthreads();
        a[t] += v;
        __syncthreads();
    }
    int totS = a[NB - 1];
    int cumS = a[t];
    __syncthreads();

    a[t] = hr[t];
    __syncthreads();
    for (int off = 1; off < NB; off <<= 1) {
        int v = (t >= off) ? a[t - off] : 0;
        __syncthreads();
        a[t] += v;
        __syncthreads();
    }
    int totR = a[NB - 1];
    cr[t] = (float)a[t] / fmaxf((float)totR, 1e-6f);
    float v = (float)cumS / fmaxf((float)totS, 1e-6f);
    __syncthreads();

    int cnt = 0;
    for (int j = 0; j < NB; j++) cnt += (cr[j] < v) ? 1 : 0;
    table[(size_t)idx * NB + t] = (uint8_t)min(cnt, 255);
}

// ---- K6: final composite, 8 px per thread, single-shot ----
__device__ __forceinline__ void proc4(uint32_t cw, uint32_t qw,
    float4 x0, float4 x1, float4 x2, float4 r0, float4 r1, float4 r2,
    const uint8_t* tb, float4& o0, float4& o1, float4& o2)
{
    float X0[4] = {x0.x, x0.y, x0.z, x0.w};
    float X1[4] = {x1.x, x1.y, x1.z, x1.w};
    float X2[4] = {x2.x, x2.y, x2.z, x2.w};
    float R0[4] = {r0.x, r0.y, r0.z, r0.w};
    float R1[4] = {r1.x, r1.y, r1.z, r1.w};
    float R2[4] = {r2.x, r2.y, r2.z, r2.w};
    #pragma unroll
    for (int j = 0; j < 4; j++) {
        uint32_t pb = (cw >> (8 * j)) & 0xFFu;
        float q = (float)((qw >> (8 * j)) & 0xFFu);
        float m0f = (float)((pb >> 2) & 1u);
        float m1f = (float)((pb >> 3) & 1u);
        float m4f = (float)((pb >> 4) & 1u);
        float fm  = (float)((pb >> 5) & 3u);
        float d0 = denorm255(X0[j]), d1 = denorm255(X1[j]), d2 = denorm255(X2[j]);
        float p0 = X0[j], p1 = X1[j], p2 = X2[j];
        {
            float e0 = renorm_lut(tb[0 * NB + min((int)(d0 * m1f), 255)]);
            float e1 = renorm_lut(tb[1 * NB + min((int)(d1 * m1f), 255)]);
            float e2 = renorm_lut(tb[2 * NB + min((int)(d2 * m1f), 255)]);
            p0 = (1.0f - m1f) * p0 + m1f * e0;
            p1 = (1.0f - m1f) * p1 + m1f * e1;
            p2 = (1.0f - m1f) * p2 + m1f * e2;
        }
        {
            float e0 = renorm_lut(tb[3 * NB + min((int)(d0 * m4f), 255)]);
            float e1 = renorm_lut(tb[4 * NB + min((int)(d1 * m4f), 255)]);
            float e2 = renorm_lut(tb[5 * NB + min((int)(d2 * m4f), 255)]);
            p0 = (1.0f - m4f) * p0 + m4f * e0;
            p1 = (1.0f - m4f) * p1 + m4f * e1;
            p2 = (1.0f - m4f) * p2 + m4f * e2;
        }
        {
            float e0 = renorm_lut(tb[6 * NB + min((int)(d0 * m0f), 255)]);
            float e1 = renorm_lut(tb[7 * NB + min((int)(d1 * m0f), 255)]);
            float e2 = renorm_lut(tb[8 * NB + min((int)(d2 * m0f), 255)]);
            p0 = (1.0f - m0f) * p0 + m0f * e0;
            p1 = (1.0f - m0f) * p1 + m0f * e1;
            p2 = (1.0f - m0f) * p2 + m0f * e2;
        }
        {
            float mb = (q * (1.0f / 25.0f)) * fm;
            float e0 = renorm_lut(tb[ 9 * NB + min((int)(d0 * fm), 255)]);
            float e1 = renorm_lut(tb[10 * NB + min((int)(d1 * fm), 255)]);
            float e2 = renorm_lut(tb[11 * NB + min((int)(d2 * fm), 255)]);
            p0 = (1.0f - mb) * p0 + mb * e0;
            p1 = (1.0f - mb) * p1 + mb * e1;
            p2 = (1.0f - mb) * p2 + mb * e2;
        }
        float a = 0.3f * m1f;
        p0 = (1.0f - a) * p0 + a * R0[j];
        p1 = (1.0f - a) * p1 + a * R1[j];
        p2 = (1.0f - a) * p2 + a * R2[j];
        a = 0.8f * fm;
        p0 = (1.0f - a) * p0 + a * R0[j];
        p1 = (1.0f - a) * p1 + a * R1[j];
        p2 = (1.0f - a) * p2 + a * R2[j];
        a = 0.1f * m0f;
        p0 = (1.0f - a) * p0 + a * R0[j];
        p1 = (1.0f - a) * p1 + a * R1[j];
        p2 = (1.0f - a) * p2 + a * R2[j];
        (&o0.x)[j] = p0; (&o1.x)[j] = p1; (&o2.x)[j] = p2;
    }
}

__global__ void __launch_bounds__(256) compose_kernel(
    const float* __restrict__ src, const float* __restrict__ tgt,
    const uint32_t* __restrict__ C, const uint32_t* __restrict__ mbs,
    const uint8_t* __restrict__ table, float* __restrict__ out)
{
    int t = blockIdx.x * 256 + threadIdx.x;   // 16 * 32768 / 256 = 2048 blocks
    int b = t >> 15;
    int c = t & 32767;                        // uint2 / float4-pair index

    __shared__ uint8_t tb[12 * NB];
    {
        const uint32_t* gt = (const uint32_t*)(table + (size_t)b * 12 * NB);
        uint32_t* tw = (uint32_t*)tb;
        for (int i = threadIdx.x; i < 12 * NB / 4; i += 256) tw[i] = gt[i];
    }
    __syncthreads();

    const float4* s0 = (const float4*)(src + (size_t)b * 3 * HW);
    const float4* s1 = s0 + HW / 4;
    const float4* s2 = s1 + HW / 4;
    const float4* t0 = (const float4*)(tgt + (size_t)b * 3 * HW);
    const float4* t1 = t0 + HW / 4;
    const float4* t2 = t1 + HW / 4;
    const uint2* pc = (const uint2*)(C + (size_t)b * (HW / 4));
    const uint2* qc = (const uint2*)(mbs + (size_t)b * (HW / 4));
    float4* o0 = (float4*)(out + (size_t)b * 3 * HW);
    float4* o1 = o0 + HW / 4;
    float4* o2 = o1 + HW / 4;

    uint2 cw = pc[c];
    uint2 qw = qc[c];
    float4 xa0 = s0[2 * c], xb0 = s0[2 * c + 1];
    float4 xa1 = s1[2 * c], xb1 = s1[2 * c + 1];
    float4 xa2 = s2[2 * c], xb2 = s2[2 * c + 1];
    float4 ra0 = t0[2 * c], rb0 = t0[2 * c + 1];
    float4 ra1 = t1[2 * c], rb1 = t1[2 * c + 1];
    float4 ra2 = t2[2 * c], rb2 = t2[2 * c + 1];

    float4 oa0, oa1, oa2, ob0, ob1, ob2;
    proc4(cw.x, qw.x, xa0, xa1, xa2, ra0, ra1, ra2, tb, oa0, oa1, oa2);
    proc4(cw.y, qw.y, xb0, xb1, xb2, rb0, rb1, rb2, tb, ob0, ob1, ob2);

    o0[2 * c] = oa0; o0[2 * c + 1] = ob0;
    o1[2 * c] = oa1; o1[2 * c + 1] = ob1;
    o2[2 * c] = oa2; o2[2 * c + 1] = ob2;
}

extern "C" void kernel_launch(void* const* d_in, const int* in_sizes, int n_in,
                              void* d_out, int out_size, void* d_ws, size_t ws_size,
                              hipStream_t stream) {
    const float* src = (const float*)d_in[0];   // (16,3,512,512)
    const float* tgt = (const float*)d_in[1];
    const float* ms  = (const float*)d_in[2];   // (16,5,512,512)
    const float* mr  = (const float*)d_in[3];
    float* out = (float*)d_out;

    uint8_t* ws = (uint8_t*)d_ws;
    uint32_t* C   = (uint32_t*)(ws);                                   // 2*BB*HW bytes
    uint32_t* mbs = (uint32_t*)(ws + (size_t)4 * BB * HW);             // BB*HW bytes
    int* hist     = (int*)(ws + (size_t)5 * BB * HW);                  // 2*BB*12*NB*4
    uint8_t* table = ws + (size_t)5 * BB * HW + (size_t)2 * BB * 12 * NB * 4;

    hipMemsetAsync(hist, 0, (size_t)2 * BB * 12 * NB * sizeof(int), stream);

    fused_mask_kernel<<<2 * BB * NYCH, 256, 0, stream>>>(ms, mr, src, tgt, C, mbs, hist);
    table_kernel<<<BB * 4 * 3, NB, 0, stream>>>(hist, table);
    compose_kernel<<<BB * (HW / 8) / 256, 256, 0, stream>>>(src, tgt, C, mbs, table, out);
}

// Round 8
// 331.689 us; speedup vs baseline: 1.0096x; 1.0096x over previous
//
#include <hip/hip_runtime.h>
#include <stdint.h>

#define BB 16
#define HH 512
#define WW 512
#define HW (HH*WW)
#define NB 256

// Fused mask kernel geometry (R7: small blocks, high residency)
#define YC 18        // owned rows per block
#define SROWS 46     // staged rows = YC + 2*14
#define MROWS 22     // mse rows = YC + 4 (blur needs +-2)
#define MPAD 132     // sMse row stride in words: 16B-aligned -> b128 blur reads
#define NYCH 29      // ceil(512/18)

// C plane byte layout (one byte per pixel, [side*BB+b][HW]):
//   bits 0-1: e = mask[2]+mask[3]  (0,1,2)
//   bit  2  : mask[0] > 0   (lip)
//   bit  3  : mask[1] > 0   (skin)
//   bit  4  : mask[4] > 0
//   bits 5-6: m_se (0,1,2)

__device__ __forceinline__ float denorm255(float x) {
    return fminf(fmaxf((x + 1.0f) * 0.5f, 0.0f), 1.0f) * 255.0f;
}
__device__ __forceinline__ float renorm_lut(int t) {
    return ((float)t / 255.0f) * 2.0f - 1.0f;
}
// byte-granular funnel shift: result byte j = byte (j+r) of (hi:lo), r in 0..3
__device__ __forceinline__ uint32_t alignb(uint32_t hi, uint32_t lo, int r) {
    return (uint32_t)(((((uint64_t)hi) << 32) | lo) >> (8 * r));
}

// 12 weighted histograms; 4 px per call
__device__ __forceinline__ void hist4(int* h, uint32_t cw,
                                      float4 v0, float4 v1, float4 v2)
{
    #pragma unroll
    for (int j = 0; j < 4; j++) {
        uint32_t pb = (cw >> (8 * j)) & 0xFFu;
        float d0 = denorm255((&v0.x)[j]);
        float d1 = denorm255((&v1.x)[j]);
        float d2 = denorm255((&v2.x)[j]);
        if (pb & 8u) {
            atomicAdd(&h[0 * NB + min((int)d0, 255)], 1);
            atomicAdd(&h[1 * NB + min((int)d1, 255)], 1);
            atomicAdd(&h[2 * NB + min((int)d2, 255)], 1);
        }
        if (pb & 16u) {
            atomicAdd(&h[3 * NB + min((int)d0, 255)], 1);
            atomicAdd(&h[4 * NB + min((int)d1, 255)], 1);
            atomicAdd(&h[5 * NB + min((int)d2, 255)], 1);
        }
        if (pb & 4u) {
            atomicAdd(&h[6 * NB + min((int)d0, 255)], 1);
            atomicAdd(&h[7 * NB + min((int)d1, 255)], 1);
            atomicAdd(&h[8 * NB + min((int)d2, 255)], 1);
        }
        int mei = (int)((pb >> 5) & 3u);
        if (mei) {
            float fm = (float)mei;
            atomicAdd(&h[ 9 * NB + min((int)(d0 * fm), 255)], mei);
            atomicAdd(&h[10 * NB + min((int)(d1 * fm), 255)], mei);
            atomicAdd(&h[11 * NB + min((int)(d2 * fm), 255)], mei);
        }
    }
}

// ---- K1 (fused): prep + hOR + vOR + m_se + blur + region histograms ----
// R7: latency-bound fix is TLP, not ILP. YC 36->18 doubles the grid to 928
// blocks; LDS trimmed to ~47.5 KB (single hist replica) -> 3 blocks/CU.
// Co-resident blocks are at different phases, so one block's LDS/VALU/atomic
// phases overlap another's global-load phase on the same CU. Plain loads +
// __syncthreads throughout (R6's asm pipeline was a measured regression).
__global__ void __launch_bounds__(256) fused_mask_kernel(
    const float* __restrict__ ms, const float* __restrict__ mr,
    const float* __restrict__ src, const float* __restrict__ tgt,
    uint32_t* __restrict__ C, uint32_t* __restrict__ mbs,
    int* __restrict__ hist)
{
    __shared__ uint32_t sHor[SROWS][128];   // 23.6 KB
    __shared__ uint32_t sMse[MROWS][MPAD];  // 11.6 KB
    __shared__ int h[12 * NB];              // 12 KB, single replica

    // XCD swizzle (928 = 8 * 116, bijective): vertically-adjacent chunks of
    // the same plane land on the same XCD -> halo re-reads hit that L2.
    int blk  = (blockIdx.x & 7) * 116 + (blockIdx.x >> 3);
    int ych  = blk % NYCH;
    int sb   = blk / NYCH;            // side*16 + b
    int side = sb >> 4;
    int b    = sb & 15;
    int y0   = ych * YC;

    const float* base = (side ? mr : ms) + (size_t)b * 5 * HW;
    int r0 = threadIdx.x >> 5;        // 0..7
    int c  = threadIdx.x & 31;        // 16-px chunk within row

    // zero hist replica
    for (int i = threadIdx.x; i < 12 * NB; i += 256) h[i] = 0;

    // ---- Phase 1: load masks, pack C bits, horizontal +-12 OR (shfl) ----
    for (int it = 0; it < 6; ++it) {
        int L  = r0 + 8 * it;         // staged row 0..45
        if (L >= SROWS) break;        // divergent exit ok: no barrier in loop
        int gy = y0 - 14 + L;         // global row
        bool inimg = (gy >= 0 && gy < HH);
        bool m1row = inimg && (L >= 12 && L < 34);   // plane1 needed (owned +-2)
        bool owned = inimg && (L >= 14 && L < 32);   // full C bits needed

        float4 v[5][4];
        #pragma unroll
        for (int p = 0; p < 5; p++)
            #pragma unroll
            for (int j = 0; j < 4; j++) v[p][j] = make_float4(0.f, 0.f, 0.f, 0.f);

        if (inimg) {
            const float* rowp = base + (size_t)gy * WW + 16 * c;
            const float4* p2 = (const float4*)(rowp + 2 * (size_t)HW);
            const float4* p3 = (const float4*)(rowp + 3 * (size_t)HW);
            #pragma unroll
            for (int j = 0; j < 4; j++) { v[2][j] = p2[j]; v[3][j] = p3[j]; }
            if (m1row) {
                const float4* p1 = (const float4*)(rowp + (size_t)HW);
                #pragma unroll
                for (int j = 0; j < 4; j++) v[1][j] = p1[j];
            }
            if (owned) {
                const float4* p0 = (const float4*)(rowp);
                const float4* p4 = (const float4*)(rowp + 4 * (size_t)HW);
                #pragma unroll
                for (int j = 0; j < 4; j++) { v[0][j] = p0[j]; v[4][j] = p4[j]; }
            }
        }

        uint32_t Wd[4], E[4];
        #pragma unroll
        for (int j = 0; j < 4; j++) {
            uint32_t wc = 0;
            #pragma unroll
            for (int k = 0; k < 4; k++) {
                float a0 = (&v[0][j].x)[k];
                float a1 = (&v[1][j].x)[k];
                float a2 = (&v[2][j].x)[k];
                float a3 = (&v[3][j].x)[k];
                float a4 = (&v[4][j].x)[k];
                uint32_t e  = (uint32_t)(a2 + a3);              // exact 0/1/2
                uint32_t pb = (a0 > 0.f ? 4u : 0u) | (a1 > 0.f ? 8u : 0u)
                            | (a4 > 0.f ? 16u : 0u);
                wc |= (e | pb) << (8 * k);
            }
            Wd[j] = wc;
            E[j]  = wc & 0x03030303u;
        }

        // halo: left lane supplies words 4c-3..4c-1, right lane 4c+4..4c+6
        uint32_t Lw[3], Rw[3];
        #pragma unroll
        for (int i = 0; i < 3; i++) {
            uint32_t lv = __shfl_up(E[i + 1], 1, 32);
            Lw[i] = (c == 0) ? 0u : lv;
            uint32_t rv = __shfl_down(E[i], 1, 32);
            Rw[i] = (c == 31) ? 0u : rv;
        }
        uint32_t arr[10] = {Lw[0], Lw[1], Lw[2], E[0], E[1], E[2], E[3],
                            Rw[0], Rw[1], Rw[2]};
        #pragma unroll
        for (int k = 0; k < 4; k++) {
            const int b3 = 3 + k;
            uint32_t a = arr[b3];
            #pragma unroll
            for (int s = 1; s <= 12; s++) {
                int ai = s >> 2, rrs = s & 3;
                uint32_t vp, vm;
                if (rrs == 0) {
                    vp = arr[b3 + ai];
                    vm = arr[b3 - ai];
                } else {
                    vp = alignb(arr[b3 + ai + 1], arr[b3 + ai], rrs);
                    int am = (s + 3) >> 2;
                    vm = alignb(arr[b3 - am + 1], arr[b3 - am], 4 - rrs);
                }
                a |= vp | vm;
            }
            sHor[L][4 * c + k] = Wd[k] | (a << 5);   // hOR value <=3 -> bits 5-6
        }
    }
    __syncthreads();

    // ---- Phase 2a: vertical +-12 OR, map 3->2, AND m1 -> sMse ----
    {
        int w  = threadIdx.x & 127;
        int mg = threadIdx.x >> 7;    // 0 or 1
        for (int k = 0; k < 11; ++k) {
            int m = mg * 11 + k;      // mse row: global y0-2+m
            uint32_t o = 0;
            #pragma unroll
            for (int dy = 0; dy < 25; ++dy) o |= sHor[m + dy][w];
            uint32_t vv = (o >> 5) & 0x03030303u;
            uint32_t t3 = vv & (vv >> 1) & 0x01010101u;   // byte==3 detector
            vv -= t3;                                      // map 3 -> 2
            uint32_t m1 = (sHor[m + 12][w] >> 3) & 0x01010101u;
            vv &= m1 * 3u;                                 // AND skin mask
            sMse[m][w] = vv;
        }
    }
    __syncthreads();

    // ---- Phase 2b: final C store (bits 0-6, no RMW) + 5x5 blur (side 0) ----
    {
        int ck = threadIdx.x & 31;
        int rr = threadIdx.x >> 5;
        size_t plane = (size_t)(side * BB + b);
        uint32_t* Cp = C + plane * (HW / 4);
        uint32_t* Mp = mbs + (size_t)b * (HW / 4);
        for (int o = rr; o < YC; o += 8) {
            int gy = y0 + o;
            if (gy >= HH) break;
            uint4 cw;
            #pragma unroll
            for (int q = 0; q < 4; q++) {
                uint32_t b5 = sHor[14 + o][4 * ck + q] & 0x1F1F1F1Fu;
                uint32_t mv = sMse[o + 2][4 * ck + q];
                (&cw.x)[q] = b5 | (mv << 5);
            }
            *((uint4*)(Cp + (size_t)gy * 128 + 4 * ck)) = cw;

            if (side == 0) {
                uint32_t s[6] = {0u, 0u, 0u, 0u, 0u, 0u};
                #pragma unroll
                for (int dy = 0; dy < 5; dy++) {
                    const uint32_t* rp = sMse[o + dy];   // global gy-2+dy
                    if (ck > 0)  s[0] += rp[4 * ck - 1];
                    s[1] += rp[4 * ck + 0];
                    s[2] += rp[4 * ck + 1];
                    s[3] += rp[4 * ck + 2];
                    s[4] += rp[4 * ck + 3];
                    if (ck < 31) s[5] += rp[4 * ck + 4];
                }
                uint4 ob;
                #pragma unroll
                for (int k = 0; k < 4; k++) {
                    uint32_t vv = s[k + 1];
                    vv += alignb(s[k + 1], s[k],     2);
                    vv += alignb(s[k + 1], s[k],     3);
                    vv += alignb(s[k + 2], s[k + 1], 1);
                    vv += alignb(s[k + 2], s[k + 1], 2);
                    (&ob.x)[k] = vv;
                }
                *((uint4*)(Mp + (size_t)gy * 128 + 4 * ck)) = ob;
            }
        }
    }

    // ---- Phase 3: region histograms (C bits from LDS + fresh image reads) ----
    {
        const float* img = (side ? tgt : src) + (size_t)b * 3 * HW;
        const float4* i0 = (const float4*)(img);
        const float4* i1 = (const float4*)(img + HW);
        const float4* i2 = (const float4*)(img + 2 * (size_t)HW);
        for (int it = 0; it < 5; ++it) {
            int idx = threadIdx.x + it * 256;
            if (idx >= YC * 64) break;          // divergent exit ok: no barrier
            int o = idx >> 6, g = idx & 63;     // owned row, 8-px group
            int gy = y0 + o;
            if (gy >= HH) continue;
            int cidx = gy * 64 + g;
            uint2 hv = *(const uint2*)&sHor[14 + o][2 * g];
            uint2 mv = *(const uint2*)&sMse[o + 2][2 * g];
            float4 a0 = i0[2 * cidx], b0v = i0[2 * cidx + 1];
            float4 a1 = i1[2 * cidx], b1v = i1[2 * cidx + 1];
            float4 a2 = i2[2 * cidx], b2v = i2[2 * cidx + 1];
            hist4(h, (hv.x & 0x1F1F1F1Fu) | (mv.x << 5), a0, a1, a2);
            hist4(h, (hv.y & 0x1F1F1F1Fu) | (mv.y << 5), b0v, b1v, b2v);
        }
    }
    __syncthreads();
    {
        int* gh = hist + (size_t)(b * 2 + side) * 12 * NB;
        for (int i = threadIdx.x; i < 12 * NB; i += 256) {
            int s = h[i];
            if (s) atomicAdd(&gh[i], s);
        }
    }
}

// ---- K5: cdf + searchsorted -> 256-entry LUT per (b, region, channel) ----
__global__ void __launch_bounds__(NB) table_kernel(
    const int* __restrict__ hist, uint8_t* __restrict__ table)
{
    int idx = blockIdx.x;               // (b*4+rg)*3+c, 192 blocks
    int c = idx % 3; int rest = idx / 3; int rg = rest & 3; int b = rest >> 2;
    const int* hs = hist + ((size_t)((b * 2 + 0) * 4 + rg) * 3 + c) * NB;
    const int* hr = hist + ((size_t)((b * 2 + 1) * 4 + rg) * 3 + c) * NB;
    __shared__ int a[NB];
    __shared__ float cr[NB];
    int t = threadIdx.x;

    a[t] = hs[t];
    __syncthreads();
    for (int off = 1; off < NB; off <<= 1) {
        int v = (t >= off) ? a[t - off] : 0;
        __syncthreads();
        a[t] += v;
        __syncthreads();
    }
    int totS = a[NB - 1];
    int cumS = a[t];
    __syncthreads();

    a[t] = hr[t];
    __syncthreads();
    for (int off = 1; off < NB; off <<= 1) {
        int v = (t >= off) ? a[t - off] : 0;
        __syncthreads();
        a[t] += v;
        __syncthreads();
    }
    int totR = a[NB - 1];
    cr[t] = (float)a[t] / fmaxf((float)totR, 1e-6f);
    float v = (float)cumS / fmaxf((float)totS, 1e-6f);
    __syncthreads();

    int cnt = 0;
    for (int j = 0; j < NB; j++) cnt += (cr[j] < v) ? 1 : 0;
    table[(size_t)idx * NB + t] = (uint8_t)min(cnt, 255);
}

// ---- K6: final composite, 8 px per thread, single-shot ----
__device__ __forceinline__ void proc4(uint32_t cw, uint32_t qw,
    float4 x0, float4 x1, float4 x2, float4 r0, float4 r1, float4 r2,
    const uint8_t* tb, float4& o0, float4& o1, float4& o2)
{
    float X0[4] = {x0.x, x0.y, x0.z, x0.w};
    float X1[4] = {x1.x, x1.y, x1.z, x1.w};
    float X2[4] = {x2.x, x2.y, x2.z, x2.w};
    float R0[4] = {r0.x, r0.y, r0.z, r0.w};
    float R1[4] = {r1.x, r1.y, r1.z, r1.w};
    float R2[4] = {r2.x, r2.y, r2.z, r2.w};
    #pragma unroll
    for (int j = 0; j < 4; j++) {
        uint32_t pb = (cw >> (8 * j)) & 0xFFu;
        float q = (float)((qw >> (8 * j)) & 0xFFu);
        float m0f = (float)((pb >> 2) & 1u);
        float m1f = (float)((pb >> 3) & 1u);
        float m4f = (float)((pb >> 4) & 1u);
        float fm  = (float)((pb >> 5) & 3u);
        float d0 = denorm255(X0[j]), d1 = denorm255(X1[j]), d2 = denorm255(X2[j]);
        float p0 = X0[j], p1 = X1[j], p2 = X2[j];
        {
            float e0 = renorm_lut(tb[0 * NB + min((int)(d0 * m1f), 255)]);
            float e1 = renorm_lut(tb[1 * NB + min((int)(d1 * m1f), 255)]);
            float e2 = renorm_lut(tb[2 * NB + min((int)(d2 * m1f), 255)]);
            p0 = (1.0f - m1f) * p0 + m1f * e0;
            p1 = (1.0f - m1f) * p1 + m1f * e1;
            p2 = (1.0f - m1f) * p2 + m1f * e2;
        }
        {
            float e0 = renorm_lut(tb[3 * NB + min((int)(d0 * m4f), 255)]);
            float e1 = renorm_lut(tb[4 * NB + min((int)(d1 * m4f), 255)]);
            float e2 = renorm_lut(tb[5 * NB + min((int)(d2 * m4f), 255)]);
            p0 = (1.0f - m4f) * p0 + m4f * e0;
            p1 = (1.0f - m4f) * p1 + m4f * e1;
            p2 = (1.0f - m4f) * p2 + m4f * e2;
        }
        {
            float e0 = renorm_lut(tb[6 * NB + min((int)(d0 * m0f), 255)]);
            float e1 = renorm_lut(tb[7 * NB + min((int)(d1 * m0f), 255)]);
            float e2 = renorm_lut(tb[8 * NB + min((int)(d2 * m0f), 255)]);
            p0 = (1.0f - m0f) * p0 + m0f * e0;
            p1 = (1.0f - m0f) * p1 + m0f * e1;
            p2 = (1.0f - m0f) * p2 + m0f * e2;
        }
        {
            float mb = (q * (1.0f / 25.0f)) * fm;
            float e0 = renorm_lut(tb[ 9 * NB + min((int)(d0 * fm), 255)]);
            float e1 = renorm_lut(tb[10 * NB + min((int)(d1 * fm), 255)]);
            float e2 = renorm_lut(tb[11 * NB + min((int)(d2 * fm), 255)]);
            p0 = (1.0f - mb) * p0 + mb * e0;
            p1 = (1.0f - mb) * p1 + mb * e1;
            p2 = (1.0f - mb) * p2 + mb * e2;
        }
        float a = 0.3f * m1f;
        p0 = (1.0f - a) * p0 + a * R0[j];
        p1 = (1.0f - a) * p1 + a * R1[j];
        p2 = (1.0f - a) * p2 + a * R2[j];
        a = 0.8f * fm;
        p0 = (1.0f - a) * p0 + a * R0[j];
        p1 = (1.0f - a) * p1 + a * R1[j];
        p2 = (1.0f - a) * p2 + a * R2[j];
        a = 0.1f * m0f;
        p0 = (1.0f - a) * p0 + a * R0[j];
        p1 = (1.0f - a) * p1 + a * R1[j];
        p2 = (1.0f - a) * p2 + a * R2[j];
        (&o0.x)[j] = p0; (&o1.x)[j] = p1; (&o2.x)[j] = p2;
    }
}

__global__ void __launch_bounds__(256) compose_kernel(
    const float* __restrict__ src, const float* __restrict__ tgt,
    const uint32_t* __restrict__ C, const uint32_t* __restrict__ mbs,
    const uint8_t* __restrict__ table, float* __restrict__ out)
{
    int t = blockIdx.x * 256 + threadIdx.x;   // 16 * 32768 / 256 = 2048 blocks
    int b = t >> 15;
    int c = t & 32767;                        // uint2 / float4-pair index

    __shared__ uint8_t tb[12 * NB];
    {
        const uint32_t* gt = (const uint32_t*)(table + (size_t)b * 12 * NB);
        uint32_t* tw = (uint32_t*)tb;
        for (int i = threadIdx.x; i < 12 * NB / 4; i += 256) tw[i] = gt[i];
    }
    __syncthreads();

    const float4* s0 = (const float4*)(src + (size_t)b * 3 * HW);
    const float4* s1 = s0 + HW / 4;
    const float4* s2 = s1 + HW / 4;
    const float4* t0 = (const float4*)(tgt + (size_t)b * 3 * HW);
    const float4* t1 = t0 + HW / 4;
    const float4* t2 = t1 + HW / 4;
    const uint2* pc = (const uint2*)(C + (size_t)b * (HW / 4));
    const uint2* qc = (const uint2*)(mbs + (size_t)b * (HW / 4));
    float4* o0 = (float4*)(out + (size_t)b * 3 * HW);
    float4* o1 = o0 + HW / 4;
    float4* o2 = o1 + HW / 4;

    uint2 cw = pc[c];
    uint2 qw = qc[c];
    float4 xa0 = s0[2 * c], xb0 = s0[2 * c + 1];
    float4 xa1 = s1[2 * c], xb1 = s1[2 * c + 1];
    float4 xa2 = s2[2 * c], xb2 = s2[2 * c + 1];
    float4 ra0 = t0[2 * c], rb0 = t0[2 * c + 1];
    float4 ra1 = t1[2 * c], rb1 = t1[2 * c + 1];
    float4 ra2 = t2[2 * c], rb2 = t2[2 * c + 1];

    float4 oa0, oa1, oa2, ob0, ob1, ob2;
    proc4(cw.x, qw.x, xa0, xa1, xa2, ra0, ra1, ra2, tb, oa0, oa1, oa2);
    proc4(cw.y, qw.y, xb0, xb1, xb2, rb0, rb1, rb2, tb, ob0, ob1, ob2);

    o0[2 * c] = oa0; o0[2 * c + 1] = ob0;
    o1[2 * c] = oa1; o1[2 * c + 1] = ob1;
    o2[2 * c] = oa2; o2[2 * c + 1] = ob2;
}

extern "C" void kernel_launch(void* const* d_in, const int* in_sizes, int n_in,
                              void* d_out, int out_size, void* d_ws, size_t ws_size,
                              hipStream_t stream) {
    const float* src = (const float*)d_in[0];   // (16,3,512,512)
    const float* tgt = (const float*)d_in[1];
    const float* ms  = (const float*)d_in[2];   // (16,5,512,512)
    const float* mr  = (const float*)d_in[3];
    float* out = (float*)d_out;

    uint8_t* ws = (uint8_t*)d_ws;
    uint32_t* C   = (uint32_t*)(ws);                                   // 2*BB*HW bytes
    uint32_t* mbs = (uint32_t*)(ws + (size_t)4 * BB * HW);             // BB*HW bytes
    int* hist     = (int*)(ws + (size_t)5 * BB * HW);                  // 2*BB*12*NB*4
    uint8_t* table = ws + (size_t)5 * BB * HW + (size_t)2 * BB * 12 * NB * 4;

    hipMemsetAsync(hist, 0, (size_t)2 * BB * 12 * NB * sizeof(int), stream);

    fused_mask_kernel<<<2 * BB * NYCH, 256, 0, stream>>>(ms, mr, src, tgt, C, mbs, hist);
    table_kernel<<<BB * 4 * 3, NB, 0, stream>>>(hist, table);
    compose_kernel<<<BB * (HW / 8) / 256, 256, 0, stream>>>(src, tgt, C, mbs, table, out);
}

// Round 9
// 323.448 us; speedup vs baseline: 1.0353x; 1.0255x over previous
//
#include <hip/hip_runtime.h>
#include <stdint.h>

#define BB 16
#define HH 512
#define WW 512
#define HW (HH*WW)
#define NB 256

// Fused mask kernel geometry (R9: demand-minimal tiling at 2 blocks/CU)
// time model: dur ~= read_demand / 3.15 TB/s (fabric read wall, established
// R0-R8: every kernel variant sits at 2.9-3.2 TB/s demand-read regardless of
// occupancy/structure; L3-warm runs identical -> wall is the read path, not HBM)
// px-reads per owned px: (2*SROWS + (YC+4) + 2*YC)/YC + 3 images
//   YC=18: 11.33   YC=32: 9.875  (-13% traffic)
#define YC 32        // owned rows per block
#define SROWS 60     // staged rows = YC + 2*14
#define MROWS 36     // mse rows = YC + 4 (blur needs +-2)
#define MPAD 132     // sMse row stride in words: 16B-aligned -> b128 blur reads
#define NYCH 16      // 512/32 exact; grid = 2*16*16 = 512 = exactly 2/CU

// C plane byte layout (one byte per pixel, [side*BB+b][HW]):
//   bits 0-1: e = mask[2]+mask[3]  (0,1,2)
//   bit  2  : mask[0] > 0   (lip)
//   bit  3  : mask[1] > 0   (skin)
//   bit  4  : mask[4] > 0
//   bits 5-6: m_se (0,1,2)

__device__ __forceinline__ float denorm255(float x) {
    return fminf(fmaxf((x + 1.0f) * 0.5f, 0.0f), 1.0f) * 255.0f;
}
__device__ __forceinline__ float renorm_lut(int t) {
    return ((float)t / 255.0f) * 2.0f - 1.0f;
}
// byte-granular funnel shift: result byte j = byte (j+r) of (hi:lo), r in 0..3
__device__ __forceinline__ uint32_t alignb(uint32_t hi, uint32_t lo, int r) {
    return (uint32_t)(((((uint64_t)hi) << 32) | lo) >> (8 * r));
}

// 12 weighted histograms; 4 px per call
__device__ __forceinline__ void hist4(int* h, uint32_t cw,
                                      float4 v0, float4 v1, float4 v2)
{
    #pragma unroll
    for (int j = 0; j < 4; j++) {
        uint32_t pb = (cw >> (8 * j)) & 0xFFu;
        float d0 = denorm255((&v0.x)[j]);
        float d1 = denorm255((&v1.x)[j]);
        float d2 = denorm255((&v2.x)[j]);
        if (pb & 8u) {
            atomicAdd(&h[0 * NB + min((int)d0, 255)], 1);
            atomicAdd(&h[1 * NB + min((int)d1, 255)], 1);
            atomicAdd(&h[2 * NB + min((int)d2, 255)], 1);
        }
        if (pb & 16u) {
            atomicAdd(&h[3 * NB + min((int)d0, 255)], 1);
            atomicAdd(&h[4 * NB + min((int)d1, 255)], 1);
            atomicAdd(&h[5 * NB + min((int)d2, 255)], 1);
        }
        if (pb & 4u) {
            atomicAdd(&h[6 * NB + min((int)d0, 255)], 1);
            atomicAdd(&h[7 * NB + min((int)d1, 255)], 1);
            atomicAdd(&h[8 * NB + min((int)d2, 255)], 1);
        }
        int mei = (int)((pb >> 5) & 3u);
        if (mei) {
            float fm = (float)mei;
            atomicAdd(&h[ 9 * NB + min((int)(d0 * fm), 255)], mei);
            atomicAdd(&h[10 * NB + min((int)(d1 * fm), 255)], mei);
            atomicAdd(&h[11 * NB + min((int)(d2 * fm), 255)], mei);
        }
    }
}

// ---- K1 (fused): prep + hOR + vOR + m_se + blur + region histograms ----
__global__ void __launch_bounds__(256) fused_mask_kernel(
    const float* __restrict__ ms, const float* __restrict__ mr,
    const float* __restrict__ src, const float* __restrict__ tgt,
    uint32_t* __restrict__ C, uint32_t* __restrict__ mbs,
    int* __restrict__ hist)
{
    __shared__ uint32_t sHor[SROWS][128];   // 30.7 KB
    __shared__ uint32_t sMse[MROWS][MPAD];  // 19.0 KB
    __shared__ int h[2][12 * NB];           // 24.6 KB (2 replicas: halves
                                            // atomic contention; total 74.3 KB
                                            // still 2 blocks/CU)

    // XCD swizzle (512 = 8 * 64, bijective): vertically-adjacent chunks of
    // the same plane land on the same XCD -> halo re-reads hit that L2.
    int blk  = (blockIdx.x & 7) * 64 + (blockIdx.x >> 3);
    int ych  = blk & 15;
    int sb   = blk >> 4;              // side*16 + b
    int side = sb >> 4;
    int b    = sb & 15;
    int y0   = ych * YC;

    const float* base = (side ? mr : ms) + (size_t)b * 5 * HW;
    int r0 = threadIdx.x >> 5;        // 0..7
    int c  = threadIdx.x & 31;        // 16-px chunk within row

    // zero hist replicas
    for (int i = threadIdx.x; i < 2 * 12 * NB; i += 256) ((int*)h)[i] = 0;

    // ---- Phase 1: load masks, pack C bits, horizontal +-12 OR (shfl) ----
    for (int it = 0; it < 8; ++it) {
        int L  = r0 + 8 * it;         // staged row 0..59
        if (L >= SROWS) break;        // divergent exit ok: no barrier in loop
        int gy = y0 - 14 + L;         // global row
        bool inimg = (gy >= 0 && gy < HH);
        bool m1row = inimg && (L >= 12 && L < 12 + YC + 4);   // plane1 (owned +-2)
        bool owned = inimg && (L >= 14 && L < 14 + YC);       // full C bits

        float4 v[5][4];
        #pragma unroll
        for (int p = 0; p < 5; p++)
            #pragma unroll
            for (int j = 0; j < 4; j++) v[p][j] = make_float4(0.f, 0.f, 0.f, 0.f);

        if (inimg) {
            const float* rowp = base + (size_t)gy * WW + 16 * c;
            const float4* p2 = (const float4*)(rowp + 2 * (size_t)HW);
            const float4* p3 = (const float4*)(rowp + 3 * (size_t)HW);
            #pragma unroll
            for (int j = 0; j < 4; j++) { v[2][j] = p2[j]; v[3][j] = p3[j]; }
            if (m1row) {
                const float4* p1 = (const float4*)(rowp + (size_t)HW);
                #pragma unroll
                for (int j = 0; j < 4; j++) v[1][j] = p1[j];
            }
            if (owned) {
                const float4* p0 = (const float4*)(rowp);
                const float4* p4 = (const float4*)(rowp + 4 * (size_t)HW);
                #pragma unroll
                for (int j = 0; j < 4; j++) { v[0][j] = p0[j]; v[4][j] = p4[j]; }
            }
        }

        uint32_t Wd[4], E[4];
        #pragma unroll
        for (int j = 0; j < 4; j++) {
            uint32_t wc = 0;
            #pragma unroll
            for (int k = 0; k < 4; k++) {
                float a0 = (&v[0][j].x)[k];
                float a1 = (&v[1][j].x)[k];
                float a2 = (&v[2][j].x)[k];
                float a3 = (&v[3][j].x)[k];
                float a4 = (&v[4][j].x)[k];
                uint32_t e  = (uint32_t)(a2 + a3);              // exact 0/1/2
                uint32_t pb = (a0 > 0.f ? 4u : 0u) | (a1 > 0.f ? 8u : 0u)
                            | (a4 > 0.f ? 16u : 0u);
                wc |= (e | pb) << (8 * k);
            }
            Wd[j] = wc;
            E[j]  = wc & 0x03030303u;
        }

        // halo: left lane supplies words 4c-3..4c-1, right lane 4c+4..4c+6
        uint32_t Lw[3], Rw[3];
        #pragma unroll
        for (int i = 0; i < 3; i++) {
            uint32_t lv = __shfl_up(E[i + 1], 1, 32);
            Lw[i] = (c == 0) ? 0u : lv;
            uint32_t rv = __shfl_down(E[i], 1, 32);
            Rw[i] = (c == 31) ? 0u : rv;
        }
        uint32_t arr[10] = {Lw[0], Lw[1], Lw[2], E[0], E[1], E[2], E[3],
                            Rw[0], Rw[1], Rw[2]};
        #pragma unroll
        for (int k = 0; k < 4; k++) {
            const int b3 = 3 + k;
            uint32_t a = arr[b3];
            #pragma unroll
            for (int s = 1; s <= 12; s++) {
                int ai = s >> 2, rrs = s & 3;
                uint32_t vp, vm;
                if (rrs == 0) {
                    vp = arr[b3 + ai];
                    vm = arr[b3 - ai];
                } else {
                    vp = alignb(arr[b3 + ai + 1], arr[b3 + ai], rrs);
                    int am = (s + 3) >> 2;
                    vm = alignb(arr[b3 - am + 1], arr[b3 - am], 4 - rrs);
                }
                a |= vp | vm;
            }
            sHor[L][4 * c + k] = Wd[k] | (a << 5);   // hOR value <=3 -> bits 5-6
        }
    }
    __syncthreads();

    // ---- Phase 2a: vertical +-12 OR, map 3->2, AND m1 -> sMse ----
    {
        int w  = threadIdx.x & 127;
        int mg = threadIdx.x >> 7;    // 0 or 1
        for (int k = 0; k < MROWS / 2; ++k) {
            int m = mg * (MROWS / 2) + k;  // mse row: global y0-2+m
            uint32_t o = 0;
            #pragma unroll
            for (int dy = 0; dy < 25; ++dy) o |= sHor[m + dy][w];
            uint32_t vv = (o >> 5) & 0x03030303u;
            uint32_t t3 = vv & (vv >> 1) & 0x01010101u;   // byte==3 detector
            vv -= t3;                                      // map 3 -> 2
            uint32_t m1 = (sHor[m + 12][w] >> 3) & 0x01010101u;
            vv &= m1 * 3u;                                 // AND skin mask
            sMse[m][w] = vv;
        }
    }
    __syncthreads();

    // ---- Phase 2b: final C store (bits 0-6, no RMW) + 5x5 blur (side 0) ----
    {
        int ck = threadIdx.x & 31;
        int rr = threadIdx.x >> 5;
        size_t plane = (size_t)(side * BB + b);
        uint32_t* Cp = C + plane * (HW / 4);
        uint32_t* Mp = mbs + (size_t)b * (HW / 4);
        for (int o = rr; o < YC; o += 8) {
            int gy = y0 + o;                 // always < HH (512 = 16*32 exact)
            uint4 cw;
            #pragma unroll
            for (int q = 0; q < 4; q++) {
                uint32_t b5 = sHor[14 + o][4 * ck + q] & 0x1F1F1F1Fu;
                uint32_t mv = sMse[o + 2][4 * ck + q];
                (&cw.x)[q] = b5 | (mv << 5);
            }
            *((uint4*)(Cp + (size_t)gy * 128 + 4 * ck)) = cw;

            if (side == 0) {
                uint32_t s[6] = {0u, 0u, 0u, 0u, 0u, 0u};
                #pragma unroll
                for (int dy = 0; dy < 5; dy++) {
                    const uint32_t* rp = sMse[o + dy];   // global gy-2+dy
                    if (ck > 0)  s[0] += rp[4 * ck - 1];
                    s[1] += rp[4 * ck + 0];
                    s[2] += rp[4 * ck + 1];
                    s[3] += rp[4 * ck + 2];
                    s[4] += rp[4 * ck + 3];
                    if (ck < 31) s[5] += rp[4 * ck + 4];
                }
                uint4 ob;
                #pragma unroll
                for (int k = 0; k < 4; k++) {
                    uint32_t vv = s[k + 1];
                    vv += alignb(s[k + 1], s[k],     2);
                    vv += alignb(s[k + 1], s[k],     3);
                    vv += alignb(s[k + 2], s[k + 1], 1);
                    vv += alignb(s[k + 2], s[k + 1], 2);
                    (&ob.x)[k] = vv;
                }
                *((uint4*)(Mp + (size_t)gy * 128 + 4 * ck)) = ob;
            }
        }
    }

    // ---- Phase 3: region histograms (C bits from LDS + fresh image reads) ----
    {
        int* hw = h[threadIdx.x >> 7];
        const float* img = (side ? tgt : src) + (size_t)b * 3 * HW;
        const float4* i0 = (const float4*)(img);
        const float4* i1 = (const float4*)(img + HW);
        const float4* i2 = (const float4*)(img + 2 * (size_t)HW);
        #pragma unroll
        for (int it = 0; it < YC * 64 / 256; ++it) {   // 8 iterations, exact
            int idx = threadIdx.x + it * 256;
            int o = idx >> 6, g = idx & 63;     // owned row, 8-px group
            int gy = y0 + o;
            int cidx = gy * 64 + g;
            uint2 hv = *(const uint2*)&sHor[14 + o][2 * g];
            uint2 mv = *(const uint2*)&sMse[o + 2][2 * g];
            float4 a0 = i0[2 * cidx], b0v = i0[2 * cidx + 1];
            float4 a1 = i1[2 * cidx], b1v = i1[2 * cidx + 1];
            float4 a2 = i2[2 * cidx], b2v = i2[2 * cidx + 1];
            hist4(hw, (hv.x & 0x1F1F1F1Fu) | (mv.x << 5), a0, a1, a2);
            hist4(hw, (hv.y & 0x1F1F1F1Fu) | (mv.y << 5), b0v, b1v, b2v);
        }
    }
    __syncthreads();
    {
        int* gh = hist + (size_t)(b * 2 + side) * 12 * NB;
        for (int i = threadIdx.x; i < 12 * NB; i += 256) {
            int s = h[0][i] + h[1][i];
            if (s) atomicAdd(&gh[i], s);
        }
    }
}

// ---- K5: cdf + searchsorted -> 256-entry LUT per (b, region, channel) ----
__global__ void __launch_bounds__(NB) table_kernel(
    const int* __restrict__ hist, uint8_t* __restrict__ table)
{
    int idx = blockIdx.x;               // (b*4+rg)*3+c, 192 blocks
    int c = idx % 3; int rest = idx / 3; int rg = rest & 3; int b = rest >> 2;
    const int* hs = hist + ((size_t)((b * 2 + 0) * 4 + rg) * 3 + c) * NB;
    const int* hr = hist + ((size_t)((b * 2 + 1) * 4 + rg) * 3 + c) * NB;
    __shared__ int a[NB];
    __shared__ float cr[NB];
    int t = threadIdx.x;

    a[t] = hs[t];
    __syncthreads();
    for (int off = 1; off < NB; off <<= 1) {
        int v = (t >= off) ? a[t - off] : 0;
        __syncthreads();
        a[t] += v;
        __syncthreads();
    }
    int totS = a[NB - 1];
    int cumS = a[t];
    __syncthreads();

    a[t] = hr[t];
    __syncthreads();
    for (int off = 1; off < NB; off <<= 1) {
        int v = (t >= off) ? a[t - off] : 0;
        __syncthreads();
        a[t] += v;
        __syncthreads();
    }
    int totR = a[NB - 1];
    cr[t] = (float)a[t] / fmaxf((float)totR, 1e-6f);
    float v = (float)cumS / fmaxf((float)totS, 1e-6f);
    __syncthreads();

    int cnt = 0;
    for (int j = 0; j < NB; j++) cnt += (cr[j] < v) ? 1 : 0;
    table[(size_t)idx * NB + t] = (uint8_t)min(cnt, 255);
}

// ---- K6: final composite, 8 px per thread, single-shot ----
__device__ __forceinline__ void proc4(uint32_t cw, uint32_t qw,
    float4 x0, float4 x1, float4 x2, float4 r0, float4 r1, float4 r2,
    const uint8_t* tb, float4& o0, float4& o1, float4& o2)
{
    float X0[4] = {x0.x, x0.y, x0.z, x0.w};
    float X1[4] = {x1.x, x1.y, x1.z, x1.w};
    float X2[4] = {x2.x, x2.y, x2.z, x2.w};
    float R0[4] = {r0.x, r0.y, r0.z, r0.w};
    float R1[4] = {r1.x, r1.y, r1.z, r1.w};
    float R2[4] = {r2.x, r2.y, r2.z, r2.w};
    #pragma unroll
    for (int j = 0; j < 4; j++) {
        uint32_t pb = (cw >> (8 * j)) & 0xFFu;
        float q = (float)((qw >> (8 * j)) & 0xFFu);
        float m0f = (float)((pb >> 2) & 1u);
        float m1f = (float)((pb >> 3) & 1u);
        float m4f = (float)((pb >> 4) & 1u);
        float fm  = (float)((pb >> 5) & 3u);
        float d0 = denorm255(X0[j]), d1 = denorm255(X1[j]), d2 = denorm255(X2[j]);
        float p0 = X0[j], p1 = X1[j], p2 = X2[j];
        {
            float e0 = renorm_lut(tb[0 * NB + min((int)(d0 * m1f), 255)]);
            float e1 = renorm_lut(tb[1 * NB + min((int)(d1 * m1f), 255)]);
            float e2 = renorm_lut(tb[2 * NB + min((int)(d2 * m1f), 255)]);
            p0 = (1.0f - m1f) * p0 + m1f * e0;
            p1 = (1.0f - m1f) * p1 + m1f * e1;
            p2 = (1.0f - m1f) * p2 + m1f * e2;
        }
        {
            float e0 = renorm_lut(tb[3 * NB + min((int)(d0 * m4f), 255)]);
            float e1 = renorm_lut(tb[4 * NB + min((int)(d1 * m4f), 255)]);
            float e2 = renorm_lut(tb[5 * NB + min((int)(d2 * m4f), 255)]);
            p0 = (1.0f - m4f) * p0 + m4f * e0;
            p1 = (1.0f - m4f) * p1 + m4f * e1;
            p2 = (1.0f - m4f) * p2 + m4f * e2;
        }
        {
            float e0 = renorm_lut(tb[6 * NB + min((int)(d0 * m0f), 255)]);
            float e1 = renorm_lut(tb[7 * NB + min((int)(d1 * m0f), 255)]);
            float e2 = renorm_lut(tb[8 * NB + min((int)(d2 * m0f), 255)]);
            p0 = (1.0f - m0f) * p0 + m0f * e0;
            p1 = (1.0f - m0f) * p1 + m0f * e1;
            p2 = (1.0f - m0f) * p2 + m0f * e2;
        }
        {
            float mb = (q * (1.0f / 25.0f)) * fm;
            float e0 = renorm_lut(tb[ 9 * NB + min((int)(d0 * fm), 255)]);
            float e1 = renorm_lut(tb[10 * NB + min((int)(d1 * fm), 255)]);
            float e2 = renorm_lut(tb[11 * NB + min((int)(d2 * fm), 255)]);
            p0 = (1.0f - mb) * p0 + mb * e0;
            p1 = (1.0f - mb) * p1 + mb * e1;
            p2 = (1.0f - mb) * p2 + mb * e2;
        }
        float a = 0.3f * m1f;
        p0 = (1.0f - a) * p0 + a * R0[j];
        p1 = (1.0f - a) * p1 + a * R1[j];
        p2 = (1.0f - a) * p2 + a * R2[j];
        a = 0.8f * fm;
        p0 = (1.0f - a) * p0 + a * R0[j];
        p1 = (1.0f - a) * p1 + a * R1[j];
        p2 = (1.0f - a) * p2 + a * R2[j];
        a = 0.1f * m0f;
        p0 = (1.0f - a) * p0 + a * R0[j];
        p1 = (1.0f - a) * p1 + a * R1[j];
        p2 = (1.0f - a) * p2 + a * R2[j];
        (&o0.x)[j] = p0; (&o1.x)[j] = p1; (&o2.x)[j] = p2;
    }
}

__global__ void __launch_bounds__(256) compose_kernel(
    const float* __restrict__ src, const float* __restrict__ tgt,
    const uint32_t* __restrict__ C, const uint32_t* __restrict__ mbs,
    const uint8_t* __restrict__ table, float* __restrict__ out)
{
    int t = blockIdx.x * 256 + threadIdx.x;   // 16 * 32768 / 256 = 2048 blocks
    int b = t >> 15;
    int c = t & 32767;                        // uint2 / float4-pair index

    __shared__ uint8_t tb[12 * NB];
    {
        const uint32_t* gt = (const uint32_t*)(table + (size_t)b * 12 * NB);
        uint32_t* tw = (uint32_t*)tb;
        for (int i = threadIdx.x; i < 12 * NB / 4; i += 256) tw[i] = gt[i];
    }
    __syncthreads();

    const float4* s0 = (const float4*)(src + (size_t)b * 3 * HW);
    const float4* s1 = s0 + HW / 4;
    const float4* s2 = s1 + HW / 4;
    const float4* t0 = (const float4*)(tgt + (size_t)b * 3 * HW);
    const float4* t1 = t0 + HW / 4;
    const float4* t2 = t1 + HW / 4;
    const uint2* pc = (const uint2*)(C + (size_t)b * (HW / 4));
    const uint2* qc = (const uint2*)(mbs + (size_t)b * (HW / 4));
    float4* o0 = (float4*)(out + (size_t)b * 3 * HW);
    float4* o1 = o0 + HW / 4;
    float4* o2 = o1 + HW / 4;

    uint2 cw = pc[c];
    uint2 qw = qc[c];
    float4 xa0 = s0[2 * c], xb0 = s0[2 * c + 1];
    float4 xa1 = s1[2 * c], xb1 = s1[2 * c + 1];
    float4 xa2 = s2[2 * c], xb2 = s2[2 * c + 1];
    float4 ra0 = t0[2 * c], rb0 = t0[2 * c + 1];
    float4 ra1 = t1[2 * c], rb1 = t1[2 * c + 1];
    float4 ra2 = t2[2 * c], rb2 = t2[2 * c + 1];

    float4 oa0, oa1, oa2, ob0, ob1, ob2;
    proc4(cw.x, qw.x, xa0, xa1, xa2, ra0, ra1, ra2, tb, oa0, oa1, oa2);
    proc4(cw.y, qw.y, xb0, xb1, xb2, rb0, rb1, rb2, tb, ob0, ob1, ob2);

    o0[2 * c] = oa0; o0[2 * c + 1] = ob0;
    o1[2 * c] = oa1; o1[2 * c + 1] = ob1;
    o2[2 * c] = oa2; o2[2 * c + 1] = ob2;
}

extern "C" void kernel_launch(void* const* d_in, const int* in_sizes, int n_in,
                              void* d_out, int out_size, void* d_ws, size_t ws_size,
                              hipStream_t stream) {
    const float* src = (const float*)d_in[0];   // (16,3,512,512)
    const float* tgt = (const float*)d_in[1];
    const float* ms  = (const float*)d_in[2];   // (16,5,512,512)
    const float* mr  = (const float*)d_in[3];
    float* out = (float*)d_out;

    uint8_t* ws = (uint8_t*)d_ws;
    uint32_t* C   = (uint32_t*)(ws);                                   // 2*BB*HW bytes
    uint32_t* mbs = (uint32_t*)(ws + (size_t)4 * BB * HW);             // BB*HW bytes
    int* hist     = (int*)(ws + (size_t)5 * BB * HW);                  // 2*BB*12*NB*4
    uint8_t* table = ws + (size_t)5 * BB * HW + (size_t)2 * BB * 12 * NB * 4;

    hipMemsetAsync(hist, 0, (size_t)2 * BB * 12 * NB * sizeof(int), stream);

    fused_mask_kernel<<<2 * BB * NYCH, 256, 0, stream>>>(ms, mr, src, tgt, C, mbs, hist);
    table_kernel<<<BB * 4 * 3, NB, 0, stream>>>(hist, table);
    compose_kernel<<<BB * (HW / 8) / 256, 256, 0, stream>>>(src, tgt, C, mbs, table, out);
}

// Round 10
// 322.486 us; speedup vs baseline: 1.0384x; 1.0030x over previous
//
#include <hip/hip_runtime.h>
#include <stdint.h>

#define BB 16
#define HH 512
#define WW 512
#define HW (HH*WW)
#define NB 256

// Fused mask kernel geometry (R9: demand-minimal tiling at 2 blocks/CU)
// time model: dur ~= read_demand / 3.15 TB/s (fabric read wall) + ~20us serial
#define YC 32        // owned rows per block
#define SROWS 60     // staged rows = YC + 2*14
#define MROWS 36     // mse rows = YC + 4 (blur needs +-2)
#define MPAD 132     // sMse row stride in words: 16B-aligned -> b128 blur reads
#define NYCH 16      // 512/32 exact; grid = 2*16*16 = 512 = exactly 2/CU

// C plane byte layout (one byte per pixel, [side*BB+b][HW]):
//   bits 0-1: e = mask[2]+mask[3]  (0,1,2)
//   bit  2  : mask[0] > 0   (lip)
//   bit  3  : mask[1] > 0   (skin)
//   bit  4  : mask[4] > 0
//   bits 5-6: m_se (0,1,2)

__device__ __forceinline__ float denorm255(float x) {
    return fminf(fmaxf((x + 1.0f) * 0.5f, 0.0f), 1.0f) * 255.0f;
}
__device__ __forceinline__ float renorm_lut(int t) {
    return ((float)t / 255.0f) * 2.0f - 1.0f;
}
// byte-granular funnel shift: result byte j = byte (j+r) of (hi:lo), r in 0..3
__device__ __forceinline__ uint32_t alignb(uint32_t hi, uint32_t lo, int r) {
    return (uint32_t)(((((uint64_t)hi) << 32) | lo) >> (8 * r));
}

// 12 weighted histograms; 4 px per call
__device__ __forceinline__ void hist4(int* h, uint32_t cw,
                                      float4 v0, float4 v1, float4 v2)
{
    #pragma unroll
    for (int j = 0; j < 4; j++) {
        uint32_t pb = (cw >> (8 * j)) & 0xFFu;
        float d0 = denorm255((&v0.x)[j]);
        float d1 = denorm255((&v1.x)[j]);
        float d2 = denorm255((&v2.x)[j]);
        if (pb & 8u) {
            atomicAdd(&h[0 * NB + min((int)d0, 255)], 1);
            atomicAdd(&h[1 * NB + min((int)d1, 255)], 1);
            atomicAdd(&h[2 * NB + min((int)d2, 255)], 1);
        }
        if (pb & 16u) {
            atomicAdd(&h[3 * NB + min((int)d0, 255)], 1);
            atomicAdd(&h[4 * NB + min((int)d1, 255)], 1);
            atomicAdd(&h[5 * NB + min((int)d2, 255)], 1);
        }
        if (pb & 4u) {
            atomicAdd(&h[6 * NB + min((int)d0, 255)], 1);
            atomicAdd(&h[7 * NB + min((int)d1, 255)], 1);
            atomicAdd(&h[8 * NB + min((int)d2, 255)], 1);
        }
        int mei = (int)((pb >> 5) & 3u);
        if (mei) {
            float fm = (float)mei;
            atomicAdd(&h[ 9 * NB + min((int)(d0 * fm), 255)], mei);
            atomicAdd(&h[10 * NB + min((int)(d1 * fm), 255)], mei);
            atomicAdd(&h[11 * NB + min((int)(d2 * fm), 255)], mei);
        }
    }
}

// ---- K1 (fused): prep + hOR + vOR + m_se + blur + region histograms ----
__global__ void __launch_bounds__(256) fused_mask_kernel(
    const float* __restrict__ ms, const float* __restrict__ mr,
    const float* __restrict__ src, const float* __restrict__ tgt,
    uint32_t* __restrict__ C, uint32_t* __restrict__ mbs,
    int* __restrict__ hist)
{
    __shared__ uint32_t sHor[SROWS][128];   // 30.7 KB
    __shared__ uint32_t sMse[MROWS][MPAD];  // 19.0 KB
    __shared__ int h[2][12 * NB];           // 24.6 KB (2 replicas)

    // XCD swizzle (512 = 8 * 64, bijective)
    int blk  = (blockIdx.x & 7) * 64 + (blockIdx.x >> 3);
    int ych  = blk & 15;
    int sb   = blk >> 4;              // side*16 + b
    int side = sb >> 4;
    int b    = sb & 15;
    int y0   = ych * YC;

    const float* base = (side ? mr : ms) + (size_t)b * 5 * HW;
    int r0 = threadIdx.x >> 5;        // 0..7
    int c  = threadIdx.x & 31;        // 16-px chunk within row

    // zero hist replicas
    for (int i = threadIdx.x; i < 2 * 12 * NB; i += 256) ((int*)h)[i] = 0;

    // ---- Phase 1: load masks, pack C bits, horizontal +-12 OR (shfl) ----
    for (int it = 0; it < 8; ++it) {
        int L  = r0 + 8 * it;         // staged row 0..59
        if (L >= SROWS) break;        // divergent exit ok: no barrier in loop
        int gy = y0 - 14 + L;         // global row
        bool inimg = (gy >= 0 && gy < HH);
        bool m1row = inimg && (L >= 12 && L < 12 + YC + 4);   // plane1 (owned +-2)
        bool owned = inimg && (L >= 14 && L < 14 + YC);       // full C bits

        float4 v[5][4];
        #pragma unroll
        for (int p = 0; p < 5; p++)
            #pragma unroll
            for (int j = 0; j < 4; j++) v[p][j] = make_float4(0.f, 0.f, 0.f, 0.f);

        if (inimg) {
            const float* rowp = base + (size_t)gy * WW + 16 * c;
            const float4* p2 = (const float4*)(rowp + 2 * (size_t)HW);
            const float4* p3 = (const float4*)(rowp + 3 * (size_t)HW);
            #pragma unroll
            for (int j = 0; j < 4; j++) { v[2][j] = p2[j]; v[3][j] = p3[j]; }
            if (m1row) {
                const float4* p1 = (const float4*)(rowp + (size_t)HW);
                #pragma unroll
                for (int j = 0; j < 4; j++) v[1][j] = p1[j];
            }
            if (owned) {
                const float4* p0 = (const float4*)(rowp);
                const float4* p4 = (const float4*)(rowp + 4 * (size_t)HW);
                #pragma unroll
                for (int j = 0; j < 4; j++) { v[0][j] = p0[j]; v[4][j] = p4[j]; }
            }
        }

        uint32_t Wd[4], E[4];
        #pragma unroll
        for (int j = 0; j < 4; j++) {
            uint32_t wc = 0;
            #pragma unroll
            for (int k = 0; k < 4; k++) {
                float a0 = (&v[0][j].x)[k];
                float a1 = (&v[1][j].x)[k];
                float a2 = (&v[2][j].x)[k];
                float a3 = (&v[3][j].x)[k];
                float a4 = (&v[4][j].x)[k];
                uint32_t e  = (uint32_t)(a2 + a3);              // exact 0/1/2
                uint32_t pb = (a0 > 0.f ? 4u : 0u) | (a1 > 0.f ? 8u : 0u)
                            | (a4 > 0.f ? 16u : 0u);
                wc |= (e | pb) << (8 * k);
            }
            Wd[j] = wc;
            E[j]  = wc & 0x03030303u;
        }

        // halo: left lane supplies words 4c-3..4c-1, right lane 4c+4..4c+6
        uint32_t Lw[3], Rw[3];
        #pragma unroll
        for (int i = 0; i < 3; i++) {
            uint32_t lv = __shfl_up(E[i + 1], 1, 32);
            Lw[i] = (c == 0) ? 0u : lv;
            uint32_t rv = __shfl_down(E[i], 1, 32);
            Rw[i] = (c == 31) ? 0u : rv;
        }
        uint32_t arr[10] = {Lw[0], Lw[1], Lw[2], E[0], E[1], E[2], E[3],
                            Rw[0], Rw[1], Rw[2]};
        #pragma unroll
        for (int k = 0; k < 4; k++) {
            const int b3 = 3 + k;
            uint32_t a = arr[b3];
            #pragma unroll
            for (int s = 1; s <= 12; s++) {
                int ai = s >> 2, rrs = s & 3;
                uint32_t vp, vm;
                if (rrs == 0) {
                    vp = arr[b3 + ai];
                    vm = arr[b3 - ai];
                } else {
                    vp = alignb(arr[b3 + ai + 1], arr[b3 + ai], rrs);
                    int am = (s + 3) >> 2;
                    vm = alignb(arr[b3 - am + 1], arr[b3 - am], 4 - rrs);
                }
                a |= vp | vm;
            }
            sHor[L][4 * c + k] = Wd[k] | (a << 5);   // hOR value <=3 -> bits 5-6
        }
    }
    __syncthreads();

    // ---- Phase 2a: vertical +-12 OR, map 3->2, AND m1 -> sMse ----
    {
        int w  = threadIdx.x & 127;
        int mg = threadIdx.x >> 7;    // 0 or 1
        for (int k = 0; k < MROWS / 2; ++k) {
            int m = mg * (MROWS / 2) + k;  // mse row: global y0-2+m
            uint32_t o = 0;
            #pragma unroll
            for (int dy = 0; dy < 25; ++dy) o |= sHor[m + dy][w];
            uint32_t vv = (o >> 5) & 0x03030303u;
            uint32_t t3 = vv & (vv >> 1) & 0x01010101u;   // byte==3 detector
            vv -= t3;                                      // map 3 -> 2
            uint32_t m1 = (sHor[m + 12][w] >> 3) & 0x01010101u;
            vv &= m1 * 3u;                                 // AND skin mask
            sMse[m][w] = vv;
        }
    }
    __syncthreads();

    // ---- Phase 2b: final C store (bits 0-6, no RMW) + 5x5 blur (side 0) ----
    {
        int ck = threadIdx.x & 31;
        int rr = threadIdx.x >> 5;
        size_t plane = (size_t)(side * BB + b);
        uint32_t* Cp = C + plane * (HW / 4);
        uint32_t* Mp = mbs + (size_t)b * (HW / 4);
        for (int o = rr; o < YC; o += 8) {
            int gy = y0 + o;                 // always < HH (512 = 16*32 exact)
            uint4 cw;
            #pragma unroll
            for (int q = 0; q < 4; q++) {
                uint32_t b5 = sHor[14 + o][4 * ck + q] & 0x1F1F1F1Fu;
                uint32_t mv = sMse[o + 2][4 * ck + q];
                (&cw.x)[q] = b5 | (mv << 5);
            }
            *((uint4*)(Cp + (size_t)gy * 128 + 4 * ck)) = cw;

            if (side == 0) {
                uint32_t s[6] = {0u, 0u, 0u, 0u, 0u, 0u};
                #pragma unroll
                for (int dy = 0; dy < 5; dy++) {
                    const uint32_t* rp = sMse[o + dy];   // global gy-2+dy
                    if (ck > 0)  s[0] += rp[4 * ck - 1];
                    s[1] += rp[4 * ck + 0];
                    s[2] += rp[4 * ck + 1];
                    s[3] += rp[4 * ck + 2];
                    s[4] += rp[4 * ck + 3];
                    if (ck < 31) s[5] += rp[4 * ck + 4];
                }
                uint4 ob;
                #pragma unroll
                for (int k = 0; k < 4; k++) {
                    uint32_t vv = s[k + 1];
                    vv += alignb(s[k + 1], s[k],     2);
                    vv += alignb(s[k + 1], s[k],     3);
                    vv += alignb(s[k + 2], s[k + 1], 1);
                    vv += alignb(s[k + 2], s[k + 1], 2);
                    (&ob.x)[k] = vv;
                }
                *((uint4*)(Mp + (size_t)gy * 128 + 4 * ck)) = ob;
            }
        }
    }

    // ---- Phase 3: region histograms (C bits from LDS + fresh image reads) ----
    {
        int* hw = h[threadIdx.x >> 7];
        const float* img = (side ? tgt : src) + (size_t)b * 3 * HW;
        const float4* i0 = (const float4*)(img);
        const float4* i1 = (const float4*)(img + HW);
        const float4* i2 = (const float4*)(img + 2 * (size_t)HW);
        #pragma unroll
        for (int it = 0; it < YC * 64 / 256; ++it) {   // 8 iterations, exact
            int idx = threadIdx.x + it * 256;
            int o = idx >> 6, g = idx & 63;     // owned row, 8-px group
            int gy = y0 + o;
            int cidx = gy * 64 + g;
            uint2 hv = *(const uint2*)&sHor[14 + o][2 * g];
            uint2 mv = *(const uint2*)&sMse[o + 2][2 * g];
            float4 a0 = i0[2 * cidx], b0v = i0[2 * cidx + 1];
            float4 a1 = i1[2 * cidx], b1v = i1[2 * cidx + 1];
            float4 a2 = i2[2 * cidx], b2v = i2[2 * cidx + 1];
            hist4(hw, (hv.x & 0x1F1F1F1Fu) | (mv.x << 5), a0, a1, a2);
            hist4(hw, (hv.y & 0x1F1F1F1Fu) | (mv.y << 5), b0v, b1v, b2v);
        }
    }
    __syncthreads();
    {
        int* gh = hist + (size_t)(b * 2 + side) * 12 * NB;
        for (int i = threadIdx.x; i < 12 * NB; i += 256) {
            int s = h[0][i] + h[1][i];
            if (s) atomicAdd(&gh[i], s);
        }
    }
}

// ---- K5: cdf + searchsorted -> 256-entry LUT per (b, region, channel) ----
__global__ void __launch_bounds__(NB) table_kernel(
    const int* __restrict__ hist, uint8_t* __restrict__ table)
{
    int idx = blockIdx.x;               // (b*4+rg)*3+c, 192 blocks
    int c = idx % 3; int rest = idx / 3; int rg = rest & 3; int b = rest >> 2;
    const int* hs = hist + ((size_t)((b * 2 + 0) * 4 + rg) * 3 + c) * NB;
    const int* hr = hist + ((size_t)((b * 2 + 1) * 4 + rg) * 3 + c) * NB;
    __shared__ int a[NB];
    __shared__ float cr[NB];
    int t = threadIdx.x;

    a[t] = hs[t];
    __syncthreads();
    for (int off = 1; off < NB; off <<= 1) {
        int v = (t >= off) ? a[t - off] : 0;
        __syncthreads();
        a[t] += v;
        __syncthreads();
    }
    int totS = a[NB - 1];
    int cumS = a[t];
    __syncthreads();

    a[t] = hr[t];
    __syncthreads();
    for (int off = 1; off < NB; off <<= 1) {
        int v = (t >= off) ? a[t - off] : 0;
        __syncthreads();
        a[t] += v;
        __syncthreads();
    }
    int totR = a[NB - 1];
    cr[t] = (float)a[t] / fmaxf((float)totR, 1e-6f);
    float v = (float)cumS / fmaxf((float)totS, 1e-6f);
    __syncthreads();

    int cnt = 0;
    for (int j = 0; j < NB; j++) cnt += (cr[j] < v) ? 1 : 0;
    table[(size_t)idx * NB + t] = (uint8_t)min(cnt, 255);
}

// ---- K6: final composite (R10: 4 px/thread for TLP; VALU was latency-
// exposed at 8 px/thread, VGPR 116, occupancy 20%) ----
__global__ void __launch_bounds__(256) compose_kernel(
    const float* __restrict__ src, const float* __restrict__ tgt,
    const uint32_t* __restrict__ C, const uint32_t* __restrict__ mbs,
    const uint8_t* __restrict__ table, float* __restrict__ out)
{
    int t = blockIdx.x * 256 + threadIdx.x;   // 16 * 65536 / 256 = 16384 blocks
    int b = t >> 16;
    int c = t & 65535;                        // float4 / uint32 index (4 px)

    __shared__ uint8_t tb[12 * NB];
    {
        const uint32_t* gt = (const uint32_t*)(table + (size_t)b * 12 * NB);
        uint32_t* tw = (uint32_t*)tb;
        for (int i = threadIdx.x; i < 12 * NB / 4; i += 256) tw[i] = gt[i];
    }
    __syncthreads();

    const float4* s0 = (const float4*)(src + (size_t)b * 3 * HW);
    const float4* s1 = s0 + HW / 4;
    const float4* s2 = s1 + HW / 4;
    const float4* t0 = (const float4*)(tgt + (size_t)b * 3 * HW);
    const float4* t1 = t0 + HW / 4;
    const float4* t2 = t1 + HW / 4;
    const uint32_t* pc = C + (size_t)b * (HW / 4);
    const uint32_t* qc = mbs + (size_t)b * (HW / 4);
    float4* o0 = (float4*)(out + (size_t)b * 3 * HW);
    float4* o1 = o0 + HW / 4;
    float4* o2 = o1 + HW / 4;

    uint32_t cw = pc[c];
    uint32_t qw = qc[c];
    float4 x0 = s0[c], x1 = s1[c], x2 = s2[c];
    float4 r0 = t0[c], r1 = t1[c], r2 = t2[c];

    float4 y0v, y1v, y2v;
    #pragma unroll
    for (int j = 0; j < 4; j++) {
        uint32_t pb = (cw >> (8 * j)) & 0xFFu;
        float q = (float)((qw >> (8 * j)) & 0xFFu);
        float m0f = (float)((pb >> 2) & 1u);
        float m1f = (float)((pb >> 3) & 1u);
        float m4f = (float)((pb >> 4) & 1u);
        float fm  = (float)((pb >> 5) & 3u);
        float X0 = (&x0.x)[j], X1 = (&x1.x)[j], X2 = (&x2.x)[j];
        float R0 = (&r0.x)[j], R1 = (&r1.x)[j], R2 = (&r2.x)[j];
        float d0 = denorm255(X0), d1 = denorm255(X1), d2 = denorm255(X2);
        float p0 = X0, p1 = X1, p2 = X2;
        {
            float e0 = renorm_lut(tb[0 * NB + min((int)(d0 * m1f), 255)]);
            float e1 = renorm_lut(tb[1 * NB + min((int)(d1 * m1f), 255)]);
            float e2 = renorm_lut(tb[2 * NB + min((int)(d2 * m1f), 255)]);
            p0 = (1.0f - m1f) * p0 + m1f * e0;
            p1 = (1.0f - m1f) * p1 + m1f * e1;
            p2 = (1.0f - m1f) * p2 + m1f * e2;
        }
        {
            float e0 = renorm_lut(tb[3 * NB + min((int)(d0 * m4f), 255)]);
            float e1 = renorm_lut(tb[4 * NB + min((int)(d1 * m4f), 255)]);
            float e2 = renorm_lut(tb[5 * NB + min((int)(d2 * m4f), 255)]);
            p0 = (1.0f - m4f) * p0 + m4f * e0;
            p1 = (1.0f - m4f) * p1 + m4f * e1;
            p2 = (1.0f - m4f) * p2 + m4f * e2;
        }
        {
            float e0 = renorm_lut(tb[6 * NB + min((int)(d0 * m0f), 255)]);
            float e1 = renorm_lut(tb[7 * NB + min((int)(d1 * m0f), 255)]);
            float e2 = renorm_lut(tb[8 * NB + min((int)(d2 * m0f), 255)]);
            p0 = (1.0f - m0f) * p0 + m0f * e0;
            p1 = (1.0f - m0f) * p1 + m0f * e1;
            p2 = (1.0f - m0f) * p2 + m0f * e2;
        }
        {
            float mb = (q * (1.0f / 25.0f)) * fm;
            float e0 = renorm_lut(tb[ 9 * NB + min((int)(d0 * fm), 255)]);
            float e1 = renorm_lut(tb[10 * NB + min((int)(d1 * fm), 255)]);
            float e2 = renorm_lut(tb[11 * NB + min((int)(d2 * fm), 255)]);
            p0 = (1.0f - mb) * p0 + mb * e0;
            p1 = (1.0f - mb) * p1 + mb * e1;
            p2 = (1.0f - mb) * p2 + mb * e2;
        }
        float a = 0.3f * m1f;
        p0 = (1.0f - a) * p0 + a * R0;
        p1 = (1.0f - a) * p1 + a * R1;
        p2 = (1.0f - a) * p2 + a * R2;
        a = 0.8f * fm;
        p0 = (1.0f - a) * p0 + a * R0;
        p1 = (1.0f - a) * p1 + a * R1;
        p2 = (1.0f - a) * p2 + a * R2;
        a = 0.1f * m0f;
        p0 = (1.0f - a) * p0 + a * R0;
        p1 = (1.0f - a) * p1 + a * R1;
        p2 = (1.0f - a) * p2 + a * R2;
        (&y0v.x)[j] = p0; (&y1v.x)[j] = p1; (&y2v.x)[j] = p2;
    }

    o0[c] = y0v;
    o1[c] = y1v;
    o2[c] = y2v;
}

extern "C" void kernel_launch(void* const* d_in, const int* in_sizes, int n_in,
                              void* d_out, int out_size, void* d_ws, size_t ws_size,
                              hipStream_t stream) {
    const float* src = (const float*)d_in[0];   // (16,3,512,512)
    const float* tgt = (const float*)d_in[1];
    const float* ms  = (const float*)d_in[2];   // (16,5,512,512)
    const float* mr  = (const float*)d_in[3];
    float* out = (float*)d_out;

    uint8_t* ws = (uint8_t*)d_ws;
    uint32_t* C   = (uint32_t*)(ws);                                   // 2*BB*HW bytes
    uint32_t* mbs = (uint32_t*)(ws + (size_t)4 * BB * HW);             // BB*HW bytes
    int* hist     = (int*)(ws + (size_t)5 * BB * HW);                  // 2*BB*12*NB*4
    uint8_t* table = ws + (size_t)5 * BB * HW + (size_t)2 * BB * 12 * NB * 4;

    hipMemsetAsync(hist, 0, (size_t)2 * BB * 12 * NB * sizeof(int), stream);

    fused_mask_kernel<<<2 * BB * NYCH, 256, 0, stream>>>(ms, mr, src, tgt, C, mbs, hist);
    table_kernel<<<BB * 4 * 3, NB, 0, stream>>>(hist, table);
    compose_kernel<<<BB * (HW / 4) / 256, 256, 0, stream>>>(src, tgt, C, mbs, table, out);
}